// Round 1
// baseline (291.545 us; speedup 1.0000x reference)
//
#include <hip/hip_runtime.h>
#include <hip/hip_bf16.h>

// Problem: B=8, H=W=48 -> 2304 positions, C=256 channels.
// corr[b,ij,kl] = (1/256) * sum_c A[b,ij,c] * B[b,kl,c]   (batched GEMM, B^T layout)
// out = corr / sqrt(sum_ij corr^2)  (per-column L2 norm over source positions)

#define HW2 2304
#define CH  256
#define NB  8
#define BK  32
#define LDK 40   // BK + 8 shorts pad -> ds_read_b128 max 2-way bank conflict (free)

typedef __attribute__((ext_vector_type(8))) short bf16x8;   // 8 bf16 = 4 VGPRs
typedef __attribute__((ext_vector_type(4))) float f32x4;    // MFMA acc

// fp32 -> bf16 round-to-nearest-even (bit trick; inputs are finite normals)
static __device__ inline short f2bf(float f) {
    union { float f; unsigned u; } x; x.f = f;
    unsigned r = x.u + 0x7FFFu + ((x.u >> 16) & 1u);
    return (short)(r >> 16);
}

__global__ __launch_bounds__(256) void corr_gemm(const float* __restrict__ A,
                                                 const float* __restrict__ B,
                                                 float* __restrict__ out,
                                                 float* __restrict__ colSumSq) {
    __shared__ short As[128 * LDK];
    __shared__ short Bs[128 * LDK];
    __shared__ float colSq[128];

    const int tid = threadIdx.x;
    const int bx = blockIdx.x;   // column tile (target positions kl)
    const int by = blockIdx.y;   // row tile (source positions ij)
    const int b  = blockIdx.z;

    if (tid < 128) colSq[tid] = 0.0f;

    const float* Ab = A + ((size_t)b * HW2 + (size_t)by * 128) * CH;
    const float* Bb = B + ((size_t)b * HW2 + (size_t)bx * 128) * CH;

    // staging decomposition: 256 threads cover 128 rows x 32 k (x4 row groups)
    const int sm = tid >> 3;          // 0..31 row within group
    const int sk = (tid & 7) * 4;     // 0,4,...,28

    const int wave = tid >> 6;        // 4 waves, 2x2 of 64x64
    const int lane = tid & 63;
    const int wm   = (wave >> 1) * 64;
    const int wn   = (wave & 1) * 64;
    const int lr   = lane & 15;
    const int quad = lane >> 4;
    const int k8   = quad * 8;

    f32x4 acc[4][4];
#pragma unroll
    for (int i = 0; i < 4; i++)
#pragma unroll
        for (int j = 0; j < 4; j++) acc[i][j] = (f32x4){0.f, 0.f, 0.f, 0.f};

    for (int kt = 0; kt < CH; kt += BK) {
        // ---- stage A,B tiles: fp32 global -> bf16 LDS ----
#pragma unroll
        for (int r = 0; r < 4; r++) {
            const int row = sm + r * 32;
            float4 va = *(const float4*)(Ab + (size_t)row * CH + kt + sk);
            float4 vb = *(const float4*)(Bb + (size_t)row * CH + kt + sk);
            short4 pa, pb;
            pa.x = f2bf(va.x); pa.y = f2bf(va.y); pa.z = f2bf(va.z); pa.w = f2bf(va.w);
            pb.x = f2bf(vb.x); pb.y = f2bf(vb.y); pb.z = f2bf(vb.z); pb.w = f2bf(vb.w);
            *(short4*)&As[row * LDK + sk] = pa;
            *(short4*)&Bs[row * LDK + sk] = pb;
        }
        __syncthreads();

        // ---- MFMA: 16 x (16x16x32) per wave ----
        bf16x8 af[4], bfr[4];
#pragma unroll
        for (int mt = 0; mt < 4; mt++)
            af[mt] = *(const bf16x8*)&As[(wm + mt * 16 + lr) * LDK + k8];
#pragma unroll
        for (int nt = 0; nt < 4; nt++)
            bfr[nt] = *(const bf16x8*)&Bs[(wn + nt * 16 + lr) * LDK + k8];
#pragma unroll
        for (int mt = 0; mt < 4; mt++)
#pragma unroll
            for (int nt = 0; nt < 4; nt++)
                acc[mt][nt] = __builtin_amdgcn_mfma_f32_16x16x32_bf16(
                    af[mt], bfr[nt], acc[mt][nt], 0, 0, 0);
        __syncthreads();
    }

    // ---- epilogue: scale, store corr, accumulate per-column sum of squares ----
    const float scale = 1.0f / (float)CH;
    const size_t outBase = (size_t)b * HW2 * HW2;
    const int colBase = bx * 128 + wn;
#pragma unroll
    for (int nt = 0; nt < 4; nt++) {
        const int col = colBase + nt * 16 + lr;
        float s = 0.f;
#pragma unroll
        for (int mt = 0; mt < 4; mt++) {
            const int row0 = by * 128 + wm + mt * 16 + quad * 4;
            f32x4 v = acc[mt][nt];
#pragma unroll
            for (int r = 0; r < 4; r++) {
                float val = v[r] * scale;
                out[outBase + (size_t)(row0 + r) * HW2 + col] = val;
                s += val * val;
            }
        }
        // combine the 4 quads (same column, different row groups)
        s += __shfl_xor(s, 16);
        s += __shfl_xor(s, 32);
        if (quad == 0) atomicAdd(&colSq[wn + nt * 16 + lr], s);
    }
    __syncthreads();
    if (tid < 128)
        atomicAdd(&colSumSq[(size_t)b * HW2 + bx * 128 + tid], colSq[tid]);
}

__global__ __launch_bounds__(256) void corr_norm(float* __restrict__ out,
                                                 const float* __restrict__ colSumSq) {
    const int n4 = NB * HW2 * (HW2 / 4);   // 10,616,832 float4
    const int per_b = HW2 * (HW2 / 4);     // float4 per batch
    for (int i = blockIdx.x * blockDim.x + threadIdx.x; i < n4;
         i += gridDim.x * blockDim.x) {
        const int b = i / per_b;
        const int col = (i * 4) % HW2;     // 4 consecutive cols, HW2 % 4 == 0
        const float* ss = colSumSq + b * HW2 + col;
        float4 v = ((float4*)out)[i];
        v.x *= rsqrtf(ss[0]);
        v.y *= rsqrtf(ss[1]);
        v.z *= rsqrtf(ss[2]);
        v.w *= rsqrtf(ss[3]);
        ((float4*)out)[i] = v;
    }
}

extern "C" void kernel_launch(void* const* d_in, const int* in_sizes, int n_in,
                              void* d_out, int out_size, void* d_ws, size_t ws_size,
                              hipStream_t stream) {
    const float* A = (const float*)d_in[0];
    const float* B = (const float*)d_in[1];
    float* out = (float*)d_out;
    float* colSumSq = (float*)d_ws;   // NB*HW2 floats = 73,728 B

    hipMemsetAsync(colSumSq, 0, (size_t)NB * HW2 * sizeof(float), stream);

    dim3 grid(HW2 / 128, HW2 / 128, NB);   // 18 x 18 x 8 = 2592 blocks
    corr_gemm<<<grid, 256, 0, stream>>>(A, B, out, colSumSq);

    corr_norm<<<4096, 256, 0, stream>>>(out, colSumSq);
}

// Round 2
// 251.686 us; speedup vs baseline: 1.1584x; 1.1584x over previous
//
#include <hip/hip_runtime.h>
#include <hip/hip_bf16.h>

// B=8, H=W=48 -> 2304 positions, C=256 channels.
// raw[b,ij,kl] = sum_c A[b,ij,c]*B[b,kl,c]
// out = raw / sqrt(sum_ij raw^2)       (the reference's 1/C cancels in the norm)
//
// Plan: (1) convert A,B fp32->bf16 into ws once; (2) GEMM pass computing only
// per-column sumsq (no 170MB store); (3) GEMM recompute pass writing the
// normalized output directly. Both passes produce bit-identical corr values.

#define HW2 2304
#define CH  256
#define NB  8
#define NELEM (NB * HW2 * CH)   // 4,718,592 per input

typedef __attribute__((ext_vector_type(8))) short bf16x8;   // 8 bf16 = 4 VGPRs
typedef __attribute__((ext_vector_type(4))) float f32x4;    // MFMA acc

static __device__ inline unsigned short f2bf(float f) {
    union { float f; unsigned u; } x; x.f = f;
    unsigned r = x.u + 0x7FFFu + ((x.u >> 16) & 1u);
    return (unsigned short)(r >> 16);
}

// async global->LDS, 16B per lane (global_load_lds_dwordx4)
static __device__ inline void async_copy16(const void* g, void* l) {
    __builtin_amdgcn_global_load_lds(
        (const __attribute__((address_space(1))) unsigned int*)g,
        (__attribute__((address_space(3))) unsigned int*)l, 16, 0, 0);
}

__global__ __launch_bounds__(256) void convert_bf16(const float* __restrict__ A,
                                                    const float* __restrict__ B,
                                                    unsigned short* __restrict__ Abf,
                                                    unsigned short* __restrict__ Bbf) {
    const int n4 = NELEM / 4;
    for (int i = blockIdx.x * blockDim.x + threadIdx.x; i < 2 * n4;
         i += gridDim.x * blockDim.x) {
        const bool isA = i < n4;
        const int j = isA ? i : i - n4;
        float4 v = (isA ? (const float4*)A : (const float4*)B)[j];
        ushort4 p;
        p.x = f2bf(v.x); p.y = f2bf(v.y); p.z = f2bf(v.z); p.w = f2bf(v.w);
        *(ushort4*)((isA ? Abf : Bbf) + (size_t)j * 4) = p;
    }
}

// Shared GEMM tile body. WRITE_OUT=false: accumulate per-column sumsq into
// colSqG. WRITE_OUT=true: recompute tile, scale by rsqrt(colSqG), store.
template <bool WRITE_OUT>
__global__ __launch_bounds__(256) void corr_pass(const unsigned short* __restrict__ Abf,
                                                 const unsigned short* __restrict__ Bbf,
                                                 float* __restrict__ colSqG,
                                                 float* __restrict__ out) {
    __shared__ unsigned short As[128 * 32];   // 8 KB, unpadded (global_load_lds layout)
    __shared__ unsigned short Bs[128 * 32];
    __shared__ float colSq[128];

    const int tid = threadIdx.x;
    const int bx = blockIdx.x;   // column tile (kl)
    const int by = blockIdx.y;   // row tile (ij)
    const int b  = blockIdx.z;

    if (!WRITE_OUT && tid < 128) colSq[tid] = 0.0f;

    const unsigned short* Ab = Abf + ((size_t)b * HW2 + (size_t)by * 128) * CH;
    const unsigned short* Bb = Bbf + ((size_t)b * HW2 + (size_t)bx * 128) * CH;

    // staging: lane covers row = tid/4 (+64*i), k-chunk = (tid&3)*8 elements (16B)
    const int srow  = tid >> 2;
    const int skcol = (tid & 3) * 8;

    const int wave = tid >> 6;   // 2x2 waves of 64x64
    const int lane = tid & 63;
    const int wm   = (wave >> 1) * 64;
    const int wn   = (wave & 1) * 64;
    const int lr   = lane & 15;
    const int quad = lane >> 4;
    const int k8   = quad * 8;

    f32x4 acc[4][4];
#pragma unroll
    for (int i = 0; i < 4; i++)
#pragma unroll
        for (int j = 0; j < 4; j++) acc[i][j] = (f32x4){0.f, 0.f, 0.f, 0.f};

    for (int kt = 0; kt < CH; kt += 32) {
#pragma unroll
        for (int i = 0; i < 2; i++) {
            async_copy16(Ab + (size_t)(srow + i * 64) * CH + kt + skcol,
                         &As[tid * 8 + i * 2048]);
            async_copy16(Bb + (size_t)(srow + i * 64) * CH + kt + skcol,
                         &Bs[tid * 8 + i * 2048]);
        }
        __syncthreads();   // waitcnt vmcnt(0) + barrier

        bf16x8 af[4], bfr[4];
#pragma unroll
        for (int mt = 0; mt < 4; mt++)
            af[mt] = *(const bf16x8*)&As[(wm + mt * 16 + lr) * 32 + k8];
#pragma unroll
        for (int nt = 0; nt < 4; nt++)
            bfr[nt] = *(const bf16x8*)&Bs[(wn + nt * 16 + lr) * 32 + k8];
#pragma unroll
        for (int mt = 0; mt < 4; mt++)
#pragma unroll
            for (int nt = 0; nt < 4; nt++)
                acc[mt][nt] = __builtin_amdgcn_mfma_f32_16x16x32_bf16(
                    af[mt], bfr[nt], acc[mt][nt], 0, 0, 0);
        __syncthreads();
    }

    const int colBase = bx * 128 + wn;
    if (!WRITE_OUT) {
        // per-column sum of squares of raw corr
#pragma unroll
        for (int nt = 0; nt < 4; nt++) {
            float s = 0.f;
#pragma unroll
            for (int mt = 0; mt < 4; mt++) {
                f32x4 v = acc[mt][nt];
#pragma unroll
                for (int r = 0; r < 4; r++) s += v[r] * v[r];
            }
            s += __shfl_xor(s, 16);
            s += __shfl_xor(s, 32);
            if (quad == 0) atomicAdd(&colSq[wn + nt * 16 + lr], s);
        }
        __syncthreads();
        if (tid < 128)
            atomicAdd(&colSqG[(size_t)b * HW2 + bx * 128 + tid], colSq[tid]);
    } else {
        const size_t outBase = (size_t)b * HW2 * HW2;
#pragma unroll
        for (int nt = 0; nt < 4; nt++) {
            const int col = colBase + nt * 16 + lr;
            const float rinv = rsqrtf(colSqG[(size_t)b * HW2 + col]);
#pragma unroll
            for (int mt = 0; mt < 4; mt++) {
                const int row0 = by * 128 + wm + mt * 16 + quad * 4;
                f32x4 v = acc[mt][nt];
#pragma unroll
                for (int r = 0; r < 4; r++)
                    out[outBase + (size_t)(row0 + r) * HW2 + col] = v[r] * rinv;
            }
        }
    }
}

extern "C" void kernel_launch(void* const* d_in, const int* in_sizes, int n_in,
                              void* d_out, int out_size, void* d_ws, size_t ws_size,
                              hipStream_t stream) {
    const float* A = (const float*)d_in[0];
    const float* B = (const float*)d_in[1];
    float* out = (float*)d_out;

    unsigned short* Abf = (unsigned short*)d_ws;          // NELEM bf16
    unsigned short* Bbf = Abf + NELEM;                    // NELEM bf16
    float* colSqG = (float*)(Bbf + NELEM);                // NB*HW2 floats (73.7 KB)

    hipMemsetAsync(colSqG, 0, (size_t)NB * HW2 * sizeof(float), stream);
    convert_bf16<<<2048, 256, 0, stream>>>(A, B, Abf, Bbf);

    dim3 grid(HW2 / 128, HW2 / 128, NB);   // 18 x 18 x 8 = 2592 blocks
    corr_pass<false><<<grid, 256, 0, stream>>>(Abf, Bbf, colSqG, out);
    corr_pass<true><<<grid, 256, 0, stream>>>(Abf, Bbf, colSqG, out);
}

// Round 3
// 237.745 us; speedup vs baseline: 1.2263x; 1.0586x over previous
//
#include <hip/hip_runtime.h>
#include <hip/hip_bf16.h>

// B=8, H=W=48 -> 2304 positions, C=256 channels.
// raw[b,ij,kl] = sum_c A[b,ij,c]*B[b,kl,c]
// out = raw / sqrt(sum_ij raw^2)       (the reference's 1/C cancels in the norm)
//
// Pipeline: (1) fp32->bf16 convert into ws; (2) GEMM pass -> per-column sumsq
// only; (3) GEMM recompute pass -> normalized output. Identical MFMA sequence
// in both passes => denominators exactly consistent with outputs.
//
// R2: K-loop does two BK=32 chunks per barrier pair (4 iters, 32 MFMA/wave
// per barrier) — keeps the 128x32 LDS tile layout (8-way bank pattern, same
// as m97) instead of 128x64 (which would be 16-way). XCD swizzle pins each
// XCD to ~one batch (4.7 MB bf16 ~ one L2).

#define HW2 2304
#define CH  256
#define NB  8
#define NELEM (NB * HW2 * CH)   // 4,718,592 per input

typedef __attribute__((ext_vector_type(8))) short bf16x8;   // 8 bf16 = 4 VGPRs
typedef __attribute__((ext_vector_type(4))) float f32x4;    // MFMA acc

static __device__ inline unsigned short f2bf(float f) {
    union { float f; unsigned u; } x; x.f = f;
    unsigned r = x.u + 0x7FFFu + ((x.u >> 16) & 1u);
    return (unsigned short)(r >> 16);
}

// async global->LDS, 16B per lane (global_load_lds_dwordx4)
static __device__ inline void async_copy16(const void* g, void* l) {
    __builtin_amdgcn_global_load_lds(
        (const __attribute__((address_space(1))) unsigned int*)g,
        (__attribute__((address_space(3))) unsigned int*)l, 16, 0, 0);
}

__global__ __launch_bounds__(256) void convert_bf16(const float* __restrict__ A,
                                                    const float* __restrict__ B,
                                                    unsigned short* __restrict__ Abf,
                                                    unsigned short* __restrict__ Bbf) {
    const int n4 = NELEM / 4;
    for (int i = blockIdx.x * blockDim.x + threadIdx.x; i < 2 * n4;
         i += gridDim.x * blockDim.x) {
        const bool isA = i < n4;
        const int j = isA ? i : i - n4;
        float4 v = (isA ? (const float4*)A : (const float4*)B)[j];
        ushort4 p;
        p.x = f2bf(v.x); p.y = f2bf(v.y); p.z = f2bf(v.z); p.w = f2bf(v.w);
        *(ushort4*)((isA ? Abf : Bbf) + (size_t)j * 4) = p;
    }
}

template <bool WRITE_OUT>
__global__ __launch_bounds__(256) void corr_pass(const unsigned short* __restrict__ Abf,
                                                 const unsigned short* __restrict__ Bbf,
                                                 float* __restrict__ colSqG,
                                                 float* __restrict__ out) {
    // two independent 128x32 chunks per matrix (NOT one 128x64 tile: keeps
    // the frag-read bank pattern at m97's level, and matches the
    // global_load_lds wave-uniform-dest layout)
    __shared__ unsigned short As[2 * 128 * 32];   // 16 KB
    __shared__ unsigned short Bs[2 * 128 * 32];   // 16 KB
    __shared__ float colSq[128];

    const int tid = threadIdx.x;

    // XCD swizzle: consecutive dispatch IDs round-robin XCDs; make batch the
    // fastest-varying coordinate so each XCD works one batch (fits its L2),
    // and bx fast within batch for A-panel reuse.
    const int lin = blockIdx.x + 18 * (blockIdx.y + 18 * blockIdx.z);
    const int b  = lin & 7;
    const int r_ = lin >> 3;          // 0..323
    const int bx = r_ % 18;           // column tile (kl)
    const int by = r_ / 18;           // row tile (ij)

    if (!WRITE_OUT && tid < 128) colSq[tid] = 0.0f;

    const unsigned short* Ab = Abf + ((size_t)b * HW2 + (size_t)by * 128) * CH;
    const unsigned short* Bb = Bbf + ((size_t)b * HW2 + (size_t)bx * 128) * CH;

    // staging: row = tid/4 (+64*i), k-chunk = (tid&3)*8 elements (16B)
    const int srow  = tid >> 2;
    const int skcol = (tid & 3) * 8;

    const int wave = tid >> 6;   // 2x2 waves of 64x64
    const int lane = tid & 63;
    const int wm   = (wave >> 1) * 64;
    const int wn   = (wave & 1) * 64;
    const int lr   = lane & 15;
    const int quad = lane >> 4;
    const int k8   = quad * 8;

    f32x4 acc[4][4];
#pragma unroll
    for (int i = 0; i < 4; i++)
#pragma unroll
        for (int j = 0; j < 4; j++) acc[i][j] = (f32x4){0.f, 0.f, 0.f, 0.f};

    for (int kt = 0; kt < CH; kt += 64) {
        // ---- stage two 32-k chunks of A and B ----
#pragma unroll
        for (int c = 0; c < 2; c++) {
            const int kof = kt + c * 32;
#pragma unroll
            for (int i = 0; i < 2; i++) {
                async_copy16(Ab + (size_t)(srow + i * 64) * CH + kof + skcol,
                             &As[c * 4096 + tid * 8 + i * 2048]);
                async_copy16(Bb + (size_t)(srow + i * 64) * CH + kof + skcol,
                             &Bs[c * 4096 + tid * 8 + i * 2048]);
            }
        }
        __syncthreads();   // vmcnt(0) drain + barrier

        // ---- 32 MFMA per wave per barrier ----
#pragma unroll
        for (int c = 0; c < 2; c++) {
            bf16x8 af[4], bfr[4];
#pragma unroll
            for (int mt = 0; mt < 4; mt++)
                af[mt] = *(const bf16x8*)&As[c * 4096 + (wm + mt * 16 + lr) * 32 + k8];
#pragma unroll
            for (int nt = 0; nt < 4; nt++)
                bfr[nt] = *(const bf16x8*)&Bs[c * 4096 + (wn + nt * 16 + lr) * 32 + k8];
#pragma unroll
            for (int mt = 0; mt < 4; mt++)
#pragma unroll
                for (int nt = 0; nt < 4; nt++)
                    acc[mt][nt] = __builtin_amdgcn_mfma_f32_16x16x32_bf16(
                        af[mt], bfr[nt], acc[mt][nt], 0, 0, 0);
        }
        __syncthreads();
    }

    const int colBase = bx * 128 + wn;
    if (!WRITE_OUT) {
#pragma unroll
        for (int nt = 0; nt < 4; nt++) {
            float s = 0.f;
#pragma unroll
            for (int mt = 0; mt < 4; mt++) {
                f32x4 v = acc[mt][nt];
#pragma unroll
                for (int r = 0; r < 4; r++) s += v[r] * v[r];
            }
            s += __shfl_xor(s, 16);
            s += __shfl_xor(s, 32);
            if (quad == 0) atomicAdd(&colSq[wn + nt * 16 + lr], s);
        }
        __syncthreads();
        if (tid < 128)
            atomicAdd(&colSqG[(size_t)b * HW2 + bx * 128 + tid], colSq[tid]);
    } else {
        const size_t outBase = (size_t)b * HW2 * HW2;
#pragma unroll
        for (int nt = 0; nt < 4; nt++) {
            const int col = colBase + nt * 16 + lr;
            const float rinv = rsqrtf(colSqG[(size_t)b * HW2 + col]);
#pragma unroll
            for (int mt = 0; mt < 4; mt++) {
                const int row0 = by * 128 + wm + mt * 16 + quad * 4;
                f32x4 v = acc[mt][nt];
#pragma unroll
                for (int r = 0; r < 4; r++)
                    out[outBase + (size_t)(row0 + r) * HW2 + col] = v[r] * rinv;
            }
        }
    }
}

extern "C" void kernel_launch(void* const* d_in, const int* in_sizes, int n_in,
                              void* d_out, int out_size, void* d_ws, size_t ws_size,
                              hipStream_t stream) {
    const float* A = (const float*)d_in[0];
    const float* B = (const float*)d_in[1];
    float* out = (float*)d_out;

    unsigned short* Abf = (unsigned short*)d_ws;          // NELEM bf16
    unsigned short* Bbf = Abf + NELEM;                    // NELEM bf16
    float* colSqG = (float*)(Bbf + NELEM);                // NB*HW2 floats (73.7 KB)

    hipMemsetAsync(colSqG, 0, (size_t)NB * HW2 * sizeof(float), stream);
    convert_bf16<<<2048, 256, 0, stream>>>(A, B, Abf, Bbf);

    dim3 grid(HW2 / 128, HW2 / 128, NB);   // 18 x 18 x 8 = 2592 blocks
    corr_pass<false><<<grid, 256, 0, stream>>>(Abf, Bbf, colSqG, out);
    corr_pass<true><<<grid, 256, 0, stream>>>(Abf, Bbf, colSqG, out);
}